// Round 2
// baseline (3475.429 us; speedup 1.0000x reference)
//
#include <hip/hip_runtime.h>

// ---------------------------------------------------------------------------
// USFM ViT (BEiT-style) forward, MI355X gfx950.
// bf16 MFMA GEMMs: triple-buffered BK=32 LDS pipeline, 2-deep global_load_lds
// prefetch with COUNTED vmcnt (never drained to 0 in the main loop), one
// s_barrier per K-step.  + MFMA flash-style attention.
// Grid is 1D with bijective XCD-chunked swizzle.
// ---------------------------------------------------------------------------

#define BATCH 32
#define NTOK 197
#define NLAYER 12
#define NRR 732
#define MROWS (BATCH * NTOK)   // 6304
#define MPAD 6400

#define NKV 224
#define QT_N 13
#define VSTR 232
#define PSTR 232
#define RPB_PER_LH (QT_N * 14 * 4 * 16 * 4)   // 46592
#define RPB_PER_L (RPB_PER_LH * 12)           // 559104
#define WL_ELEMS 8257536                       // qkv+proj+fc1+fc2 per layer

typedef __attribute__((ext_vector_type(8))) short bf16x8_t;
typedef __attribute__((ext_vector_type(4))) float f32x4_t;

__device__ __forceinline__ unsigned short f2bf_rn(float f) {
  unsigned u = __float_as_uint(f);
  unsigned r = (u + 0x7FFFu + ((u >> 16) & 1u)) >> 16;
  return (unsigned short)r;
}
__device__ __forceinline__ float bf2f(unsigned short u) {
  return __uint_as_float(((unsigned)u) << 16);
}

__device__ __forceinline__ void gld16(const unsigned short* g, unsigned short* l) {
  __builtin_amdgcn_global_load_lds(
      (const __attribute__((address_space(1))) unsigned int*)g,
      (__attribute__((address_space(3))) unsigned int*)l, 16, 0, 0);
}

// ---------------------------------------------------------------------------
// fp32 -> bf16 converters
// ---------------------------------------------------------------------------
__global__ void cvt4(const float4* __restrict__ s, ushort4* __restrict__ d, int n4) {
  int i = blockIdx.x * 256 + threadIdx.x;
  if (i >= n4) return;
  float4 v = s[i];
  ushort4 r;
  r.x = f2bf_rn(v.x); r.y = f2bf_rn(v.y); r.z = f2bf_rn(v.z); r.w = f2bf_rn(v.w);
  d[i] = r;
}

__global__ void cvt_layer(const float4* __restrict__ qw, const float4* __restrict__ pw,
                          const float4* __restrict__ f1, const float4* __restrict__ f2,
                          ushort4* __restrict__ dst) {
  const int n_q = 2304 * 768 / 4;
  const int n_p = 768 * 768 / 4;
  const int n_1 = 3072 * 768 / 4;
  int i = blockIdx.x * 256 + threadIdx.x;
  float4 v;
  if (i < n_q) v = qw[i];
  else if (i < n_q + n_p) v = pw[i - n_q];
  else if (i < n_q + n_p + n_1) v = f1[i - n_q - n_p];
  else if (i < n_q + n_p + 2 * n_1) v = f2[i - n_q - n_p - n_1];
  else return;
  ushort4 r;
  r.x = f2bf_rn(v.x); r.y = f2bf_rn(v.y); r.z = f2bf_rn(v.z); r.w = f2bf_rn(v.w);
  dst[i] = r;
}

// ---------------------------------------------------------------------------
// rel-pos bias, fragment order, mask baked in
// ---------------------------------------------------------------------------
__global__ void build_rpb(const float* __restrict__ rt, const int* __restrict__ ridx,
                          unsigned short* __restrict__ dst) {
  int idx = blockIdx.x * 256 + threadIdx.x;
  if (idx >= RPB_PER_L * NLAYER) return;
  int r = idx & 3;
  int fr = (idx >> 2) & 15;
  int fq = (idx >> 6) & 3;
  int t2 = idx >> 8;
  int jt = t2 % 14; t2 /= 14;
  int qt = t2 % QT_N; t2 /= QT_N;
  int h = t2 % 12;
  int l = t2 / 12;
  int row = qt * 16 + fq * 4 + r;
  int col = jt * 16 + fr;
  float v = -30000.f;
  if (row < 197 && col < 197)
    v = rt[((size_t)l * NRR + ridx[row * 197 + col]) * 12 + h];
  dst[idx] = f2bf_rn(v);
}

// ---------------------------------------------------------------------------
// patch unfold
// ---------------------------------------------------------------------------
__global__ void build_xp(const float* __restrict__ x, unsigned short* __restrict__ xp) {
  int idx = blockIdx.x * 256 + threadIdx.x;
  if (idx >= 6272 * 768) return;
  int r = idx / 768, c = idx - r * 768;
  int b = r / 196, p = r - b * 196;
  int gy = p / 14, gx = p - gy * 14;
  int ch = c >> 8, rem = c & 255, py = rem >> 4, px = rem & 15;
  float v = x[(((size_t)b * 3 + ch) * 224 + gy * 16 + py) * 224 + gx * 16 + px];
  xp[(size_t)(b * 197 + 1 + p) * 768 + c] = f2bf_rn(v);
}

__global__ void fill_cls(const float* __restrict__ cls, float* __restrict__ tok) {
  int idx = blockIdx.x * 256 + threadIdx.x;
  int b = idx / 768, d = idx - b * 768;
  tok[(size_t)(b * 197) * 768 + d] = cls[d];
}

// ---------------------------------------------------------------------------
// LayerNorm rows: fp32 in -> bf16 out
// ---------------------------------------------------------------------------
__global__ __launch_bounds__(256) void ln_rows(const float* __restrict__ x,
                                               unsigned short* __restrict__ y,
                                               const float* __restrict__ g,
                                               const float* __restrict__ b) {
  int row = blockIdx.x;
  const float* xr = x + (size_t)row * 768;
  int t = threadIdx.x;
  float v0 = xr[t], v1 = xr[t + 256], v2 = xr[t + 512];
  float s = v0 + v1 + v2;
  float q = v0 * v0 + v1 * v1 + v2 * v2;
  for (int off = 32; off; off >>= 1) { s += __shfl_xor(s, off); q += __shfl_xor(q, off); }
  __shared__ float rs[4], rq[4];
  int wave = t >> 6;
  if ((t & 63) == 0) { rs[wave] = s; rq[wave] = q; }
  __syncthreads();
  s = rs[0] + rs[1] + rs[2] + rs[3];
  q = rq[0] + rq[1] + rq[2] + rq[3];
  float mean = s * (1.f / 768.f);
  float var = q * (1.f / 768.f) - mean * mean;
  float rstd = rsqrtf(var + 1e-5f);
  unsigned short* yr = y + (size_t)row * 768;
  yr[t]       = f2bf_rn((v0 - mean) * rstd * g[t]       + b[t]);
  yr[t + 256] = f2bf_rn((v1 - mean) * rstd * g[t + 256] + b[t + 256]);
  yr[t + 512] = f2bf_rn((v2 - mean) * rstd * g[t + 512] + b[t + 512]);
}

// ---------------------------------------------------------------------------
// MFMA GEMM: out = A[M,K] @ Bw[N,K]^T, bf16 in, fp32 accum.
// BM x 128 tile; BK=32 per K-step, TRIPLE-BUFFERED with 2-deep prefetch:
//   prologue: stage(slot0,t0); stage(slot1,t1)
//   iter t:   vmcnt(LPS)  [cur's loads landed; t+1's stay in flight]
//             s_barrier    [all waves ready; separates prev reads from stage]
//             stage(slot(t+2), t+2)   [slot last read at iter t-1 -> safe]
//             ds_read + MFMA on slot(t)
// vmcnt is COUNTED (LPS = per-wave loads/stage), drained to 0 only at the
// final step (T4: counted vmcnt is the lever; drain-0 ≈ no pipeline).
// LDS chunk-swizzle per 32-k tile: store chunk (lane&3)^((lane>>3)&3); read
// chunk fq^((fr>>1)&3) -> conflict-free octets (verified: conflicts=0).
// Grid 1D; bijective XCD-chunked swizzle (m204).
// MODE 0: Cf = acc + bias; 1: qkv epilogue; 2: residual; 3: gelu
// ---------------------------------------------------------------------------
template <int MODE, int BM>
__global__ __launch_bounds__(256, (BM == 64 ? 4 : 3)) void gemm_t(
    const unsigned short* __restrict__ A, const unsigned short* __restrict__ Bw,
    float* __restrict__ Cf, unsigned short* __restrict__ Cb,
    const float* __restrict__ bias, const float* __restrict__ bias2,
    const float* __restrict__ gamma, int K, int N, int nbx) {
  constexpr int MI = BM / 32;   // acc tiles in M per wave
  constexpr int AG = BM / 64;   // A gld16 issues per wave per stage
  constexpr int LPS = AG + 2;   // per-wave gld16s per stage (A + B)
  __shared__ __align__(16) unsigned short As[3][BM * 32];
  __shared__ __align__(16) unsigned short Bs[3][128 * 32];
  const int tid = threadIdx.x;
  const int wave = tid >> 6, lane = tid & 63;

  // XCD-chunked bijective swizzle (m204)
  const int nwg = gridDim.x;
  const int q8 = nwg >> 3, r8 = nwg & 7;
  const int xcd = blockIdx.x & 7, ii = blockIdx.x >> 3;
  const int wg = (xcd < r8 ? xcd * (q8 + 1) : r8 * (q8 + 1) + (xcd - r8) * q8) + ii;
  const int m0 = (wg / nbx) * BM, n0 = (wg % nbx) * 128;

  const int wm = (wave & 1) * (MI * 16), wn = (wave >> 1) * 64;
  f32x4_t acc[MI][4] = {};
  const int srow = lane >> 2;
  const int scol = ((lane & 3) ^ ((lane >> 3) & 3)) * 8;   // swizzled source chunk
  const unsigned short* Abase = A + (size_t)(m0 + srow) * K + scol;
  const unsigned short* Bbase = Bw + (size_t)(n0 + srow) * K + scol;
  const int fr = lane & 15, fq = lane >> 4;
  const int rchunk = (fq ^ ((fr >> 1) & 3)) * 8;           // swizzled read chunk

  auto stage = [&](int slot, int k0) {
#pragma unroll
    for (int u0 = 0; u0 < AG; ++u0) {
      int u = wave + u0 * 4;
      gld16(Abase + (size_t)(u * 16) * K + k0, &As[slot][u * 512]);
    }
#pragma unroll
    for (int u0 = 0; u0 < 2; ++u0) {
      int u = wave + u0 * 4;
      gld16(Bbase + (size_t)(u * 16) * K + k0, &Bs[slot][u * 512]);
    }
  };

  const int nk = K >> 5;
  // prologue: 2-deep prefetch
  stage(0, 0);
  stage(1, 32);

  int cur = 0;
  for (int t = 0; t < nk; ++t) {
    // wait for cur's loads only; keep t+1's (and later t+2's) in flight
    if (t + 1 < nk) {
      if constexpr (LPS == 3) asm volatile("s_waitcnt vmcnt(3)" ::: "memory");
      else                    asm volatile("s_waitcnt vmcnt(4)" ::: "memory");
    } else {
      asm volatile("s_waitcnt vmcnt(0)" ::: "memory");
    }
    // all waves: cur landed; also orders iter t-1's ds_reads before the
    // stage below (slot (t+2)%3 was last read at iter t-1).
    asm volatile("s_barrier" ::: "memory");
    if (t + 2 < nk) {
      int s2 = cur + 2; if (s2 >= 3) s2 -= 3;
      stage(s2, (t + 2) << 5);
    }
    {
      bf16x8_t af[MI], bfr[4];
#pragma unroll
      for (int i = 0; i < MI; ++i)
        af[i] = *(const bf16x8_t*)(&As[cur][(wm + i * 16 + fr) * 32 + rchunk]);
#pragma unroll
      for (int j = 0; j < 4; ++j)
        bfr[j] = *(const bf16x8_t*)(&Bs[cur][(wn + j * 16 + fr) * 32 + rchunk]);
#pragma unroll
      for (int i = 0; i < MI; ++i)
#pragma unroll
        for (int j = 0; j < 4; ++j)
          acc[i][j] = __builtin_amdgcn_mfma_f32_16x16x32_bf16(af[i], bfr[j], acc[i][j], 0, 0, 0);
    }
    ++cur; if (cur == 3) cur = 0;
  }

  const int er = (lane >> 4) * 4;
  const int ec = lane & 15;
#pragma unroll
  for (int i = 0; i < MI; ++i) {
#pragma unroll
    for (int j = 0; j < 4; ++j) {
#pragma unroll
      for (int r = 0; r < 4; ++r) {
        int row = m0 + wm + i * 16 + er + r;
        int col = n0 + wn + j * 16 + ec;
        float v = acc[i][j][r];
        size_t idx = (size_t)row * N + col;
        if constexpr (MODE == 0) {
          Cf[idx] = v + bias[col];
        } else if constexpr (MODE == 1) {
          float bv = (col < 768) ? bias[col] : (col >= 1536 ? bias2[col - 1536] : 0.f);
          v += bv;
          if (col < 768) v *= 0.125f;  // SCALE = 64^-0.5
          Cb[idx] = f2bf_rn(v);
        } else if constexpr (MODE == 2) {
          Cf[idx] = Cf[idx] + gamma[col] * (v + bias[col]);
        } else {
          float tt = v + bias[col];
          float gv = 0.5f * tt * (1.f + erff(tt * 0.70710678118654752f));
          Cb[idx] = f2bf_rn(gv);
        }
      }
    }
  }
}

// ---------------------------------------------------------------------------
// MFMA attention: one block per (b,h), 4 waves, q-tiles striped over waves.
// ---------------------------------------------------------------------------
__global__ __launch_bounds__(256) void attn_mfma(
    const unsigned short* __restrict__ qkv,
    const unsigned short* __restrict__ rpb,
    unsigned short* __restrict__ o) {
  const int bh = blockIdx.x;
  const int b = bh / 12, h = bh - b * 12;
  __shared__ __align__(16) unsigned short Vt[64 * VSTR];
  __shared__ __align__(16) unsigned short Pls[4][16 * PSTR];
  const int t = threadIdx.x;
  const int wave = t >> 6, lane = t & 63;
  const int fr = lane & 15, fq = lane >> 4;
  const size_t qbase = (size_t)(b * 197) * 2304 + h * 64;
  const unsigned short* rph = rpb + (size_t)h * RPB_PER_LH;

  for (int idx = t; idx < NKV * 16; idx += 256) {
    int j = idx >> 4, d0 = (idx & 15) * 4;
    ushort4 v = *(const ushort4*)(qkv + qbase + 1536 + (size_t)j * 2304 + d0);
    Vt[(d0 + 0) * VSTR + j] = v.x;
    Vt[(d0 + 1) * VSTR + j] = v.y;
    Vt[(d0 + 2) * VSTR + j] = v.z;
    Vt[(d0 + 3) * VSTR + j] = v.w;
  }
  __syncthreads();

  unsigned short* P = &Pls[wave][0];
  for (int qt = wave; qt < QT_N; qt += 4) {
    const unsigned short* qrow = qkv + qbase + (size_t)(qt * 16 + fr) * 2304 + fq * 8;
    bf16x8_t qa0 = *(const bf16x8_t*)(qrow);
    bf16x8_t qa1 = *(const bf16x8_t*)(qrow + 32);
    f32x4_t S[14];
#pragma unroll
    for (int jt = 0; jt < 14; ++jt) {
      const unsigned short* krow = qkv + qbase + 768 + (size_t)(jt * 16 + fr) * 2304 + fq * 8;
      bf16x8_t kb0 = *(const bf16x8_t*)(krow);
      bf16x8_t kb1 = *(const bf16x8_t*)(krow + 32);
      f32x4_t s = {};
      s = __builtin_amdgcn_mfma_f32_16x16x32_bf16(qa0, kb0, s, 0, 0, 0);
      s = __builtin_amdgcn_mfma_f32_16x16x32_bf16(qa1, kb1, s, 0, 0, 0);
      ushort4 rb = *(const ushort4*)(rph + ((size_t)(qt * 14 + jt) * 4 + fq) * 64 + fr * 4);
      s[0] += bf2f(rb.x); s[1] += bf2f(rb.y); s[2] += bf2f(rb.z); s[3] += bf2f(rb.w);
      S[jt] = s;
    }
    float mx[4], sum[4];
#pragma unroll
    for (int r = 0; r < 4; ++r) mx[r] = S[0][r];
#pragma unroll
    for (int jt = 1; jt < 14; ++jt)
#pragma unroll
      for (int r = 0; r < 4; ++r) mx[r] = fmaxf(mx[r], S[jt][r]);
#pragma unroll
    for (int r = 0; r < 4; ++r) {
      for (int off = 1; off < 16; off <<= 1) mx[r] = fmaxf(mx[r], __shfl_xor(mx[r], off));
      sum[r] = 0.f;
    }
#pragma unroll
    for (int jt = 0; jt < 14; ++jt) {
#pragma unroll
      for (int r = 0; r < 4; ++r) {
        float p = __expf(S[jt][r] - mx[r]);
        sum[r] += p;
        P[(fq * 4 + r) * PSTR + jt * 16 + fr] = f2bf_rn(p);
      }
    }
    float rinv[4];
#pragma unroll
    for (int r = 0; r < 4; ++r) {
      for (int off = 1; off < 16; off <<= 1) sum[r] += __shfl_xor(sum[r], off);
      rinv[r] = 1.f / sum[r];
    }
    bf16x8_t pa[7];
#pragma unroll
    for (int ks = 0; ks < 7; ++ks)
      pa[ks] = *(const bf16x8_t*)(P + fr * PSTR + ks * 32 + fq * 8);
#pragma unroll
    for (int nt = 0; nt < 4; ++nt) {
      f32x4_t O = {};
#pragma unroll
      for (int ks = 0; ks < 7; ++ks) {
        bf16x8_t vb = *(const bf16x8_t*)(Vt + (nt * 16 + fr) * VSTR + ks * 32 + fq * 8);
        O = __builtin_amdgcn_mfma_f32_16x16x32_bf16(pa[ks], vb, O, 0, 0, 0);
      }
#pragma unroll
      for (int r = 0; r < 4; ++r) {
        int row = qt * 16 + fq * 4 + r;
        if (row < 197)
          o[(size_t)(b * 197 + row) * 768 + h * 64 + nt * 16 + fr] = f2bf_rn(O[r] * rinv[r]);
      }
    }
  }
}

// ---------------------------------------------------------------------------
// final: mean over patch tokens + fc_norm
// ---------------------------------------------------------------------------
__global__ __launch_bounds__(256) void pool_ln(const float* __restrict__ tok,
                                               const float* __restrict__ g,
                                               const float* __restrict__ bb,
                                               float* __restrict__ out) {
  int b = blockIdx.x;
  __shared__ float pool[768];
  int t = threadIdx.x;
  for (int c = t; c < 768; c += 256) {
    float s = 0.f;
    const float* p = tok + (size_t)(b * 197 + 1) * 768 + c;
    for (int i = 0; i < 196; ++i) s += p[(size_t)i * 768];
    pool[c] = s * (1.f / 196.f);
  }
  __syncthreads();
  float s = 0.f, q = 0.f;
  for (int c = t; c < 768; c += 256) { float v = pool[c]; s += v; q += v * v; }
  for (int off = 32; off; off >>= 1) { s += __shfl_xor(s, off); q += __shfl_xor(q, off); }
  __shared__ float rs[4], rq[4];
  if ((t & 63) == 0) { rs[t >> 6] = s; rq[t >> 6] = q; }
  __syncthreads();
  s = rs[0] + rs[1] + rs[2] + rs[3];
  q = rq[0] + rq[1] + rq[2] + rq[3];
  float mean = s * (1.f / 768.f);
  float var = q * (1.f / 768.f) - mean * mean;
  float rstd = rsqrtf(var + 1e-5f);
  for (int c = t; c < 768; c += 256)
    out[(size_t)b * 768 + c] = (pool[c] - mean) * rstd * g[c] + bb[c];
}

// ---------------------------------------------------------------------------
extern "C" void kernel_launch(void* const* d_in, const int* in_sizes, int n_in,
                              void* d_out, int out_size, void* d_ws, size_t ws_size,
                              hipStream_t stream) {
  const float* x         = (const float*)d_in[0];
  const float* patch_w   = (const float*)d_in[1];
  const float* patch_b   = (const float*)d_in[2];
  const float* cls_tok   = (const float*)d_in[3];
  const float* ln1_g     = (const float*)d_in[4];
  const float* ln1_b     = (const float*)d_in[5];
  const float* qkv_w     = (const float*)d_in[6];
  const float* q_bias    = (const float*)d_in[7];
  const float* v_bias    = (const float*)d_in[8];
  const float* rel_table = (const float*)d_in[9];
  const float* proj_w    = (const float*)d_in[10];
  const float* proj_b    = (const float*)d_in[11];
  const float* gamma1    = (const float*)d_in[12];
  const float* ln2_g     = (const float*)d_in[13];
  const float* ln2_b     = (const float*)d_in[14];
  const float* fc1_w     = (const float*)d_in[15];
  const float* fc1_b     = (const float*)d_in[16];
  const float* fc2_w     = (const float*)d_in[17];
  const float* fc2_b     = (const float*)d_in[18];
  const float* gamma2    = (const float*)d_in[19];
  const float* fcn_g     = (const float*)d_in[20];
  const float* fcn_b     = (const float*)d_in[21];
  const int* rel_index   = (const int*)d_in[22];
  float* out = (float*)d_out;

  char* ws = (char*)d_ws;
  size_t off = 0;
  auto take = [&](size_t bytes) {
    char* p = ws + off;
    off += (bytes + 255) & ~(size_t)255;
    return p;
  };
  unsigned short* wl     = (unsigned short*)take((size_t)WL_ELEMS * 2);
  unsigned short* pwb    = (unsigned short*)take((size_t)589824 * 2);
  float*          tokf   = (float*)take((size_t)MPAD * 768 * 4);
  unsigned short* hb     = (unsigned short*)take((size_t)MPAD * 768 * 2);
  unsigned short* qkvb   = (unsigned short*)take((size_t)MPAD * 2304 * 2);
  unsigned short* ffb    = (unsigned short*)take((size_t)MPAD * 3072 * 2);
  unsigned short* rpbAll = (unsigned short*)take((size_t)RPB_PER_L * NLAYER * 2);
  unsigned short* xp = ffb;
  unsigned short* ob = hb;
  unsigned short* wl_qkv = wl;
  unsigned short* wl_proj = wl + (size_t)2304 * 768;
  unsigned short* wl_fc1 = wl_proj + (size_t)768 * 768;
  unsigned short* wl_fc2 = wl_fc1 + (size_t)3072 * 768;

  // one-time: rel-pos bias expansion
  build_rpb<<<(RPB_PER_L * NLAYER + 255) / 256, 256, 0, stream>>>(rel_table, rel_index, rpbAll);

  // patch embed
  cvt4<<<576, 256, 0, stream>>>((const float4*)patch_w, (ushort4*)pwb, 147456);
  build_xp<<<18816, 256, 0, stream>>>(x, xp);
  gemm_t<0, 64><<<600, 256, 0, stream>>>(xp, pwb, tokf, nullptr, patch_b,
                                         nullptr, nullptr, 768, 768, 6);
  fill_cls<<<96, 256, 0, stream>>>(cls_tok, tokf);

  for (int l = 0; l < NLAYER; ++l) {
    cvt_layer<<<(WL_ELEMS / 4 + 255) / 256, 256, 0, stream>>>(
        (const float4*)(qkv_w + (size_t)l * 2304 * 768),
        (const float4*)(proj_w + (size_t)l * 768 * 768),
        (const float4*)(fc1_w + (size_t)l * 3072 * 768),
        (const float4*)(fc2_w + (size_t)l * 768 * 3072), (ushort4*)wl);
    ln_rows<<<MROWS, 256, 0, stream>>>(tokf, hb, ln1_g + l * 768, ln1_b + l * 768);
    gemm_t<1, 128><<<900, 256, 0, stream>>>(hb, wl_qkv, nullptr, qkvb,
                                            q_bias + l * 768, v_bias + l * 768,
                                            nullptr, 768, 2304, 18);
    attn_mfma<<<384, 256, 0, stream>>>(qkvb, rpbAll + (size_t)l * RPB_PER_L, ob);
    gemm_t<2, 64><<<600, 256, 0, stream>>>(ob, wl_proj, tokf, nullptr,
                                           proj_b + l * 768, nullptr,
                                           gamma1 + l * 768, 768, 768, 6);
    ln_rows<<<MROWS, 256, 0, stream>>>(tokf, hb, ln2_g + l * 768, ln2_b + l * 768);
    gemm_t<3, 128><<<1200, 256, 0, stream>>>(hb, wl_fc1, nullptr, ffb,
                                             fc1_b + l * 3072, nullptr, nullptr,
                                             768, 3072, 24);
    gemm_t<2, 64><<<600, 256, 0, stream>>>(ffb, wl_fc2, tokf, nullptr,
                                           fc2_b + l * 768, nullptr,
                                           gamma2 + l * 768, 3072, 768, 6);
  }
  pool_ln<<<32, 256, 0, stream>>>(tokf, fcn_g, fcn_b, out);
}

// Round 4
// 3336.267 us; speedup vs baseline: 1.0417x; 1.0417x over previous
//
#include <hip/hip_runtime.h>

// ---------------------------------------------------------------------------
// USFM ViT (BEiT-style) forward, MI355X gfx950.
// bf16 MFMA GEMMs: BK=32, THREE NAMED LDS buffers (distinct objects so the
// waitcnt pass can prove ds_read does NOT alias in-flight global_load_lds
// prefetches), 1-deep prefetch, counted vmcnt BEFORE each barrier, one
// barrier per K-step, setprio around MFMA.  + MFMA flash attention.
// Grid is 1D with bijective XCD-chunked swizzle.
// (Round-3 resubmission: identical schedule; builtin s_barrier hardening.)
// ---------------------------------------------------------------------------

#define BATCH 32
#define NTOK 197
#define NLAYER 12
#define NRR 732
#define MROWS (BATCH * NTOK)   // 6304
#define MPAD 6400

#define NKV 224
#define QT_N 13
#define VSTR 232
#define PSTR 232
#define RPB_PER_LH (QT_N * 14 * 4 * 16 * 4)   // 46592
#define RPB_PER_L (RPB_PER_LH * 12)           // 559104
#define WL_ELEMS 8257536                       // qkv+proj+fc1+fc2 per layer

typedef __attribute__((ext_vector_type(8))) short bf16x8_t;
typedef __attribute__((ext_vector_type(4))) float f32x4_t;

__device__ __forceinline__ unsigned short f2bf_rn(float f) {
  unsigned u = __float_as_uint(f);
  unsigned r = (u + 0x7FFFu + ((u >> 16) & 1u)) >> 16;
  return (unsigned short)r;
}
__device__ __forceinline__ float bf2f(unsigned short u) {
  return __uint_as_float(((unsigned)u) << 16);
}

__device__ __forceinline__ void gld16(const unsigned short* g, unsigned short* l) {
  __builtin_amdgcn_global_load_lds(
      (const __attribute__((address_space(1))) unsigned int*)g,
      (__attribute__((address_space(3))) unsigned int*)l, 16, 0, 0);
}

// ---------------------------------------------------------------------------
// fp32 -> bf16 converters
// ---------------------------------------------------------------------------
__global__ void cvt4(const float4* __restrict__ s, ushort4* __restrict__ d, int n4) {
  int i = blockIdx.x * 256 + threadIdx.x;
  if (i >= n4) return;
  float4 v = s[i];
  ushort4 r;
  r.x = f2bf_rn(v.x); r.y = f2bf_rn(v.y); r.z = f2bf_rn(v.z); r.w = f2bf_rn(v.w);
  d[i] = r;
}

__global__ void cvt_layer(const float4* __restrict__ qw, const float4* __restrict__ pw,
                          const float4* __restrict__ f1, const float4* __restrict__ f2,
                          ushort4* __restrict__ dst) {
  const int n_q = 2304 * 768 / 4;
  const int n_p = 768 * 768 / 4;
  const int n_1 = 3072 * 768 / 4;
  int i = blockIdx.x * 256 + threadIdx.x;
  float4 v;
  if (i < n_q) v = qw[i];
  else if (i < n_q + n_p) v = pw[i - n_q];
  else if (i < n_q + n_p + n_1) v = f1[i - n_q - n_p];
  else if (i < n_q + n_p + 2 * n_1) v = f2[i - n_q - n_p - n_1];
  else return;
  ushort4 r;
  r.x = f2bf_rn(v.x); r.y = f2bf_rn(v.y); r.z = f2bf_rn(v.z); r.w = f2bf_rn(v.w);
  dst[i] = r;
}

// ---------------------------------------------------------------------------
// rel-pos bias, fragment order, mask baked in
// ---------------------------------------------------------------------------
__global__ void build_rpb(const float* __restrict__ rt, const int* __restrict__ ridx,
                          unsigned short* __restrict__ dst) {
  int idx = blockIdx.x * 256 + threadIdx.x;
  if (idx >= RPB_PER_L * NLAYER) return;
  int r = idx & 3;
  int fr = (idx >> 2) & 15;
  int fq = (idx >> 6) & 3;
  int t2 = idx >> 8;
  int jt = t2 % 14; t2 /= 14;
  int qt = t2 % QT_N; t2 /= QT_N;
  int h = t2 % 12;
  int l = t2 / 12;
  int row = qt * 16 + fq * 4 + r;
  int col = jt * 16 + fr;
  float v = -30000.f;
  if (row < 197 && col < 197)
    v = rt[((size_t)l * NRR + ridx[row * 197 + col]) * 12 + h];
  dst[idx] = f2bf_rn(v);
}

// ---------------------------------------------------------------------------
// patch unfold
// ---------------------------------------------------------------------------
__global__ void build_xp(const float* __restrict__ x, unsigned short* __restrict__ xp) {
  int idx = blockIdx.x * 256 + threadIdx.x;
  if (idx >= 6272 * 768) return;
  int r = idx / 768, c = idx - r * 768;
  int b = r / 196, p = r - b * 196;
  int gy = p / 14, gx = p - gy * 14;
  int ch = c >> 8, rem = c & 255, py = rem >> 4, px = rem & 15;
  float v = x[(((size_t)b * 3 + ch) * 224 + gy * 16 + py) * 224 + gx * 16 + px];
  xp[(size_t)(b * 197 + 1 + p) * 768 + c] = f2bf_rn(v);
}

__global__ void fill_cls(const float* __restrict__ cls, float* __restrict__ tok) {
  int idx = blockIdx.x * 256 + threadIdx.x;
  int b = idx / 768, d = idx - b * 768;
  tok[(size_t)(b * 197) * 768 + d] = cls[d];
}

// ---------------------------------------------------------------------------
// LayerNorm rows: fp32 in -> bf16 out
// ---------------------------------------------------------------------------
__global__ __launch_bounds__(256) void ln_rows(const float* __restrict__ x,
                                               unsigned short* __restrict__ y,
                                               const float* __restrict__ g,
                                               const float* __restrict__ b) {
  int row = blockIdx.x;
  const float* xr = x + (size_t)row * 768;
  int t = threadIdx.x;
  float v0 = xr[t], v1 = xr[t + 256], v2 = xr[t + 512];
  float s = v0 + v1 + v2;
  float q = v0 * v0 + v1 * v1 + v2 * v2;
  for (int off = 32; off; off >>= 1) { s += __shfl_xor(s, off); q += __shfl_xor(q, off); }
  __shared__ float rs[4], rq[4];
  int wave = t >> 6;
  if ((t & 63) == 0) { rs[wave] = s; rq[wave] = q; }
  __syncthreads();
  s = rs[0] + rs[1] + rs[2] + rs[3];
  q = rq[0] + rq[1] + rq[2] + rq[3];
  float mean = s * (1.f / 768.f);
  float var = q * (1.f / 768.f) - mean * mean;
  float rstd = rsqrtf(var + 1e-5f);
  unsigned short* yr = y + (size_t)row * 768;
  yr[t]       = f2bf_rn((v0 - mean) * rstd * g[t]       + b[t]);
  yr[t + 256] = f2bf_rn((v1 - mean) * rstd * g[t + 256] + b[t + 256]);
  yr[t + 512] = f2bf_rn((v2 - mean) * rstd * g[t + 512] + b[t + 512]);
}

// ---------------------------------------------------------------------------
// MFMA GEMM: out = A[M,K] @ Bw[N,K]^T, bf16 in, fp32 accum.
// BM x 128 tile; BK=32 per K-step. THREE NAMED LDS slot pairs (As0..2 /
// Bs0..2) so ds_read of slot t provably does not alias the in-flight DMA
// into slot t+1 -> waitcnt pass must not drain the prefetch.
// Phase p (slots rotate 0,1,2):
//   stage(slot p+1, k_{t+1})    [1-deep prefetch]
//   vmcnt(LPS)                  [own slot-t loads retired; prefetch in flight]
//   s_barrier                   [=> ALL waves' slot-t data resident]
//   ds_read(slot p) + MFMA      [setprio(1) around cluster]
// Tail phase waits vmcnt(0). WAR: slot p+1 last read two barriers earlier
// (every wave's ds_reads of a slot are consumed by its MFMAs BEFORE its next
// barrier, so after that barrier the slot is dead and DMA-writable).
// Requires K % 96 == 0 (768, 3072 ok).
// LDS chunk-swizzle per 32-k tile: store chunk (lane&3)^((lane>>3)&3); read
// chunk fq^((fr>>1)&3) -> conflict-free octets (verified: conflicts=0).
// Grid 1D; bijective XCD-chunked swizzle (m204).
// MODE 0: Cf = acc + bias; 1: qkv epilogue; 2: residual; 3: gelu
// ---------------------------------------------------------------------------
template <int MODE, int BM>
__global__ __launch_bounds__(256, (BM == 64 ? 4 : 3)) void gemm_t(
    const unsigned short* __restrict__ A, const unsigned short* __restrict__ Bw,
    float* __restrict__ Cf, unsigned short* __restrict__ Cb,
    const float* __restrict__ bias, const float* __restrict__ bias2,
    const float* __restrict__ gamma, int K, int N, int nbx) {
  constexpr int MI = BM / 32;   // acc tiles in M per wave
  constexpr int AG = BM / 64;   // A gld16 issues per wave per stage
  constexpr int LPS = AG + 2;   // per-wave gld16s per stage (A + B)
  __shared__ __align__(16) unsigned short As0[BM * 32];
  __shared__ __align__(16) unsigned short As1[BM * 32];
  __shared__ __align__(16) unsigned short As2[BM * 32];
  __shared__ __align__(16) unsigned short Bs0[128 * 32];
  __shared__ __align__(16) unsigned short Bs1[128 * 32];
  __shared__ __align__(16) unsigned short Bs2[128 * 32];
  const int tid = threadIdx.x;
  const int wave = tid >> 6, lane = tid & 63;

  // XCD-chunked bijective swizzle (m204)
  const int nwg = gridDim.x;
  const int q8 = nwg >> 3, r8 = nwg & 7;
  const int xcd = blockIdx.x & 7, ii = blockIdx.x >> 3;
  const int wg = (xcd < r8 ? xcd * (q8 + 1) : r8 * (q8 + 1) + (xcd - r8) * q8) + ii;
  const int m0 = (wg / nbx) * BM, n0 = (wg % nbx) * 128;

  const int wm = (wave & 1) * (MI * 16), wn = (wave >> 1) * 64;
  f32x4_t acc[MI][4] = {};
  const int srow = lane >> 2;
  const int scol = ((lane & 3) ^ ((lane >> 3) & 3)) * 8;   // swizzled source chunk
  const int fr = lane & 15, fq = lane >> 4;
  const int rchunk = (fq ^ ((fr >> 1) & 3)) * 8;           // swizzled read chunk

  // hoisted per-wave global row pointers (kills per-step 64-bit addr VALU)
  const unsigned short* pa[AG];
  const unsigned short* pb[2];
#pragma unroll
  for (int u0 = 0; u0 < AG; ++u0)
    pa[u0] = A + (size_t)(m0 + (wave + u0 * 4) * 16 + srow) * K + scol;
#pragma unroll
  for (int u0 = 0; u0 < 2; ++u0)
    pb[u0] = Bw + (size_t)(n0 + (wave + u0 * 4) * 16 + srow) * K + scol;

  auto stage = [&](unsigned short* Asl, unsigned short* Bsl, int k0) {
#pragma unroll
    for (int u0 = 0; u0 < AG; ++u0)
      gld16(pa[u0] + k0, Asl + (wave + u0 * 4) * 512);
#pragma unroll
    for (int u0 = 0; u0 < 2; ++u0)
      gld16(pb[u0] + k0, Bsl + (wave + u0 * 4) * 512);
  };

  auto compute = [&](const unsigned short* Asl, const unsigned short* Bsl) {
    bf16x8_t af[MI], bfr[4];
#pragma unroll
    for (int i = 0; i < MI; ++i)
      af[i] = *(const bf16x8_t*)(Asl + (wm + i * 16 + fr) * 32 + rchunk);
#pragma unroll
    for (int j = 0; j < 4; ++j)
      bfr[j] = *(const bf16x8_t*)(Bsl + (wn + j * 16 + fr) * 32 + rchunk);
    __builtin_amdgcn_s_setprio(1);
#pragma unroll
    for (int i = 0; i < MI; ++i)
#pragma unroll
      for (int j = 0; j < 4; ++j)
        acc[i][j] = __builtin_amdgcn_mfma_f32_16x16x32_bf16(af[i], bfr[j], acc[i][j], 0, 0, 0);
    __builtin_amdgcn_s_setprio(0);
  };

  auto waitN = [&]() {
    if constexpr (LPS == 3) asm volatile("s_waitcnt vmcnt(3)" ::: "memory");
    else                    asm volatile("s_waitcnt vmcnt(4)" ::: "memory");
  };
  auto wait0 = [&]() { asm volatile("s_waitcnt vmcnt(0)" ::: "memory"); };

  const int nk = K >> 5;          // multiple of 3 (K % 96 == 0)
  stage(As0, Bs0, 0);
  for (int t0 = 0; t0 < nk; t0 += 3) {
    // phase 0: compute slot0, prefetch slot1
    if (t0 + 1 < nk) { stage(As1, Bs1, (t0 + 1) << 5); waitN(); }
    else             { wait0(); }
    __builtin_amdgcn_s_barrier();
    compute(As0, Bs0);
    // phase 1: compute slot1, prefetch slot2
    if (t0 + 2 < nk) { stage(As2, Bs2, (t0 + 2) << 5); waitN(); }
    else             { wait0(); }
    __builtin_amdgcn_s_barrier();
    compute(As1, Bs1);
    // phase 2: compute slot2, prefetch slot0 (next macro-iter)
    if (t0 + 3 < nk) { stage(As0, Bs0, (t0 + 3) << 5); waitN(); }
    else             { wait0(); }
    __builtin_amdgcn_s_barrier();
    compute(As2, Bs2);
  }

  const int er = (lane >> 4) * 4;
  const int ec = lane & 15;
#pragma unroll
  for (int i = 0; i < MI; ++i) {
#pragma unroll
    for (int j = 0; j < 4; ++j) {
#pragma unroll
      for (int r = 0; r < 4; ++r) {
        int row = m0 + wm + i * 16 + er + r;
        int col = n0 + wn + j * 16 + ec;
        float v = acc[i][j][r];
        size_t idx = (size_t)row * N + col;
        if constexpr (MODE == 0) {
          Cf[idx] = v + bias[col];
        } else if constexpr (MODE == 1) {
          float bv = (col < 768) ? bias[col] : (col >= 1536 ? bias2[col - 1536] : 0.f);
          v += bv;
          if (col < 768) v *= 0.125f;  // SCALE = 64^-0.5
          Cb[idx] = f2bf_rn(v);
        } else if constexpr (MODE == 2) {
          Cf[idx] = Cf[idx] + gamma[col] * (v + bias[col]);
        } else {
          float tt = v + bias[col];
          float gv = 0.5f * tt * (1.f + erff(tt * 0.70710678118654752f));
          Cb[idx] = f2bf_rn(gv);
        }
      }
    }
  }
}

// ---------------------------------------------------------------------------
// MFMA attention: one block per (b,h), 4 waves, q-tiles striped over waves.
// ---------------------------------------------------------------------------
__global__ __launch_bounds__(256) void attn_mfma(
    const unsigned short* __restrict__ qkv,
    const unsigned short* __restrict__ rpb,
    unsigned short* __restrict__ o) {
  const int bh = blockIdx.x;
  const int b = bh / 12, h = bh - b * 12;
  __shared__ __align__(16) unsigned short Vt[64 * VSTR];
  __shared__ __align__(16) unsigned short Pls[4][16 * PSTR];
  const int t = threadIdx.x;
  const int wave = t >> 6, lane = t & 63;
  const int fr = lane & 15, fq = lane >> 4;
  const size_t qbase = (size_t)(b * 197) * 2304 + h * 64;
  const unsigned short* rph = rpb + (size_t)h * RPB_PER_LH;

  for (int idx = t; idx < NKV * 16; idx += 256) {
    int j = idx >> 4, d0 = (idx & 15) * 4;
    ushort4 v = *(const ushort4*)(qkv + qbase + 1536 + (size_t)j * 2304 + d0);
    Vt[(d0 + 0) * VSTR + j] = v.x;
    Vt[(d0 + 1) * VSTR + j] = v.y;
    Vt[(d0 + 2) * VSTR + j] = v.z;
    Vt[(d0 + 3) * VSTR + j] = v.w;
  }
  __syncthreads();

  unsigned short* P = &Pls[wave][0];
  for (int qt = wave; qt < QT_N; qt += 4) {
    const unsigned short* qrow = qkv + qbase + (size_t)(qt * 16 + fr) * 2304 + fq * 8;
    bf16x8_t qa0 = *(const bf16x8_t*)(qrow);
    bf16x8_t qa1 = *(const bf16x8_t*)(qrow + 32);
    f32x4_t S[14];
#pragma unroll
    for (int jt = 0; jt < 14; ++jt) {
      const unsigned short* krow = qkv + qbase + 768 + (size_t)(jt * 16 + fr) * 2304 + fq * 8;
      bf16x8_t kb0 = *(const bf16x8_t*)(krow);
      bf16x8_t kb1 = *(const bf16x8_t*)(krow + 32);
      f32x4_t s = {};
      s = __builtin_amdgcn_mfma_f32_16x16x32_bf16(qa0, kb0, s, 0, 0, 0);
      s = __builtin_amdgcn_mfma_f32_16x16x32_bf16(qa1, kb1, s, 0, 0, 0);
      ushort4 rb = *(const ushort4*)(rph + ((size_t)(qt * 14 + jt) * 4 + fq) * 64 + fr * 4);
      s[0] += bf2f(rb.x); s[1] += bf2f(rb.y); s[2] += bf2f(rb.z); s[3] += bf2f(rb.w);
      S[jt] = s;
    }
    float mx[4], sum[4];
#pragma unroll
    for (int r = 0; r < 4; ++r) mx[r] = S[0][r];
#pragma unroll
    for (int jt = 1; jt < 14; ++jt)
#pragma unroll
      for (int r = 0; r < 4; ++r) mx[r] = fmaxf(mx[r], S[jt][r]);
#pragma unroll
    for (int r = 0; r < 4; ++r) {
      for (int off = 1; off < 16; off <<= 1) mx[r] = fmaxf(mx[r], __shfl_xor(mx[r], off));
      sum[r] = 0.f;
    }
#pragma unroll
    for (int jt = 0; jt < 14; ++jt) {
#pragma unroll
      for (int r = 0; r < 4; ++r) {
        float p = __expf(S[jt][r] - mx[r]);
        sum[r] += p;
        P[(fq * 4 + r) * PSTR + jt * 16 + fr] = f2bf_rn(p);
      }
    }
    float rinv[4];
#pragma unroll
    for (int r = 0; r < 4; ++r) {
      for (int off = 1; off < 16; off <<= 1) sum[r] += __shfl_xor(sum[r], off);
      rinv[r] = 1.f / sum[r];
    }
    bf16x8_t pa[7];
#pragma unroll
    for (int ks = 0; ks < 7; ++ks)
      pa[ks] = *(const bf16x8_t*)(P + fr * PSTR + ks * 32 + fq * 8);
#pragma unroll
    for (int nt = 0; nt < 4; ++nt) {
      f32x4_t O = {};
#pragma unroll
      for (int ks = 0; ks < 7; ++ks) {
        bf16x8_t vb = *(const bf16x8_t*)(Vt + (nt * 16 + fr) * VSTR + ks * 32 + fq * 8);
        O = __builtin_amdgcn_mfma_f32_16x16x32_bf16(pa[ks], vb, O, 0, 0, 0);
      }
#pragma unroll
      for (int r = 0; r < 4; ++r) {
        int row = qt * 16 + fq * 4 + r;
        if (row < 197)
          o[(size_t)(b * 197 + row) * 768 + h * 64 + nt * 16 + fr] = f2bf_rn(O[r] * rinv[r]);
      }
    }
  }
}

// ---------------------------------------------------------------------------
// final: mean over patch tokens + fc_norm
// ---------------------------------------------------------------------------
__global__ __launch_bounds__(256) void pool_ln(const float* __restrict__ tok,
                                               const float* __restrict__ g,
                                               const float* __restrict__ bb,
                                               float* __restrict__ out) {
  int b = blockIdx.x;
  __shared__ float pool[768];
  int t = threadIdx.x;
  for (int c = t; c < 768; c += 256) {
    float s = 0.f;
    const float* p = tok + (size_t)(b * 197 + 1) * 768 + c;
    for (int i = 0; i < 196; ++i) s += p[(size_t)i * 768];
    pool[c] = s * (1.f / 196.f);
  }
  __syncthreads();
  float s = 0.f, q = 0.f;
  for (int c = t; c < 768; c += 256) { float v = pool[c]; s += v; q += v * v; }
  for (int off = 32; off; off >>= 1) { s += __shfl_xor(s, off); q += __shfl_xor(q, off); }
  __shared__ float rs[4], rq[4];
  if ((t & 63) == 0) { rs[t >> 6] = s; rq[t >> 6] = q; }
  __syncthreads();
  s = rs[0] + rs[1] + rs[2] + rs[3];
  q = rq[0] + rq[1] + rq[2] + rq[3];
  float mean = s * (1.f / 768.f);
  float var = q * (1.f / 768.f) - mean * mean;
  float rstd = rsqrtf(var + 1e-5f);
  for (int c = t; c < 768; c += 256)
    out[(size_t)b * 768 + c] = (pool[c] - mean) * rstd * g[c] + bb[c];
}

// ---------------------------------------------------------------------------
extern "C" void kernel_launch(void* const* d_in, const int* in_sizes, int n_in,
                              void* d_out, int out_size, void* d_ws, size_t ws_size,
                              hipStream_t stream) {
  const float* x         = (const float*)d_in[0];
  const float* patch_w   = (const float*)d_in[1];
  const float* patch_b   = (const float*)d_in[2];
  const float* cls_tok   = (const float*)d_in[3];
  const float* ln1_g     = (const float*)d_in[4];
  const float* ln1_b     = (const float*)d_in[5];
  const float* qkv_w     = (const float*)d_in[6];
  const float* q_bias    = (const float*)d_in[7];
  const float* v_bias    = (const float*)d_in[8];
  const float* rel_table = (const float*)d_in[9];
  const float* proj_w    = (const float*)d_in[10];
  const float* proj_b    = (const float*)d_in[11];
  const float* gamma1    = (const float*)d_in[12];
  const float* ln2_g     = (const float*)d_in[13];
  const float* ln2_b     = (const float*)d_in[14];
  const float* fc1_w     = (const float*)d_in[15];
  const float* fc1_b     = (const float*)d_in[16];
  const float* fc2_w     = (const float*)d_in[17];
  const float* fc2_b     = (const float*)d_in[18];
  const float* gamma2    = (const float*)d_in[19];
  const float* fcn_g     = (const float*)d_in[20];
  const float* fcn_b     = (const float*)d_in[21];
  const int* rel_index   = (const int*)d_in[22];
  float* out = (float*)d_out;

  char* ws = (char*)d_ws;
  size_t off = 0;
  auto take = [&](size_t bytes) {
    char* p = ws + off;
    off += (bytes + 255) & ~(size_t)255;
    return p;
  };
  unsigned short* wl     = (unsigned short*)take((size_t)WL_ELEMS * 2);
  unsigned short* pwb    = (unsigned short*)take((size_t)589824 * 2);
  float*          tokf   = (float*)take((size_t)MPAD * 768 * 4);
  unsigned short* hb     = (unsigned short*)take((size_t)MPAD * 768 * 2);
  unsigned short* qkvb   = (unsigned short*)take((size_t)MPAD * 2304 * 2);
  unsigned short* ffb    = (unsigned short*)take((size_t)MPAD * 3072 * 2);
  unsigned short* rpbAll = (unsigned short*)take((size_t)RPB_PER_L * NLAYER * 2);
  unsigned short* xp = ffb;
  unsigned short* ob = hb;
  unsigned short* wl_qkv = wl;
  unsigned short* wl_proj = wl + (size_t)2304 * 768;
  unsigned short* wl_fc1 = wl_proj + (size_t)768 * 768;
  unsigned short* wl_fc2 = wl_fc1 + (size_t)3072 * 768;

  // one-time: rel-pos bias expansion
  build_rpb<<<(RPB_PER_L * NLAYER + 255) / 256, 256, 0, stream>>>(rel_table, rel_index, rpbAll);

  // patch embed
  cvt4<<<576, 256, 0, stream>>>((const float4*)patch_w, (ushort4*)pwb, 147456);
  build_xp<<<18816, 256, 0, stream>>>(x, xp);
  gemm_t<0, 64><<<600, 256, 0, stream>>>(xp, pwb, tokf, nullptr, patch_b,
                                         nullptr, nullptr, 768, 768, 6);
  fill_cls<<<96, 256, 0, stream>>>(cls_tok, tokf);

  for (int l = 0; l < NLAYER; ++l) {
    cvt_layer<<<(WL_ELEMS / 4 + 255) / 256, 256, 0, stream>>>(
        (const float4*)(qkv_w + (size_t)l * 2304 * 768),
        (const float4*)(proj_w + (size_t)l * 768 * 768),
        (const float4*)(fc1_w + (size_t)l * 3072 * 768),
        (const float4*)(fc2_w + (size_t)l * 768 * 3072), (ushort4*)wl);
    ln_rows<<<MROWS, 256, 0, stream>>>(tokf, hb, ln1_g + l * 768, ln1_b + l * 768);
    gemm_t<1, 128><<<900, 256, 0, stream>>>(hb, wl_qkv, nullptr, qkvb,
                                            q_bias + l * 768, v_bias + l * 768,
                                            nullptr, 768, 2304, 18);
    attn_mfma<<<384, 256, 0, stream>>>(qkvb, rpbAll + (size_t)l * RPB_PER_L, ob);
    gemm_t<2, 64><<<600, 256, 0, stream>>>(ob, wl_proj, tokf, nullptr,
                                           proj_b + l * 768, nullptr,
                                           gamma1 + l * 768, 768, 768, 6);
    ln_rows<<<MROWS, 256, 0, stream>>>(tokf, hb, ln2_g + l * 768, ln2_b + l * 768);
    gemm_t<3, 128><<<1200, 256, 0, stream>>>(hb, wl_fc1, nullptr, ffb,
                                             fc1_b + l * 3072, nullptr, nullptr,
                                             768, 3072, 24);
    gemm_t<2, 64><<<600, 256, 0, stream>>>(ffb, wl_fc2, tokf, nullptr,
                                           fc2_b + l * 768, nullptr,
                                           gamma2 + l * 768, 3072, 768, 6);
  }
  pool_ln<<<32, 256, 0, stream>>>(tokf, fcn_g, fcn_b, out);
}